// Round 3
// baseline (242.685 us; speedup 1.0000x reference)
//
#include <hip/hip_runtime.h>
#include <hip/hip_bf16.h>

// 3-layer SplineConv (3x3, degree 2, open spline). Atomic-free, deep fusion.
// Round 21: streaming message writes. m_phase previously stored each edge's
//   64B message at its dst-CSR slot (random 64B = half-line scatter ->
//   suspected L2 read-for-ownership: ~51MB phantom fetch + full-line
//   writeback per layer; tm0 FETCH_SIZE 60MB vs 19MB ideal). Now m_phase
//   stores msg[e] at the SRC-CSR position (e is the loop index): each wave
//   writes 1KB contiguous, full lines, no RFO. Consumers use a one-time
//   pos[] indirection (pos[dst_slot] = src_slot, built in scatter_plain)
//   and do random 64B READS (bounded 2x line amplification, latency hidden
//   by pos-prefetch software pipeline + ~24 waves/CU).
// Pipeline: init | count+rank | scan1 | scan3 | scatter(atomic-free) |
//   L1 tm0 | L2 gtm | L3 gtm | final gather.  TN=32 tiles, 18.9 KB LDS,
//   per-tile MFMA acc write-through (VGPR<=64, 8 blocks/CU), erec prefetch.

typedef __attribute__((ext_vector_type(8))) short short8;
typedef __attribute__((ext_vector_type(4))) float f32x4;

__device__ __forceinline__ float blo(unsigned u) {
    union { unsigned u; float f; } x; x.u = u << 16; return x.f;
}
__device__ __forceinline__ float bhi(unsigned u) {
    union { unsigned u; float f; } x; x.u = u & 0xffff0000u; return x.f;
}
__device__ __forceinline__ unsigned short f2bf(float f) {
    union { float f; unsigned u; } x; x.f = f;
    unsigned r = x.u + 0x7fffu + ((x.u >> 16) & 1u);   // RNE
    return (unsigned short)(r >> 16);
}
__device__ __forceinline__ short8 cvt8(const float* p) {
    float4 a = *(const float4*)p;
    float4 b = *(const float4*)(p + 4);
    short8 r;
    r[0] = (short)f2bf(a.x); r[1] = (short)f2bf(a.y);
    r[2] = (short)f2bf(a.z); r[3] = (short)f2bf(a.w);
    r[4] = (short)f2bf(b.x); r[5] = (short)f2bf(b.y);
    r[6] = (short)f2bf(b.z); r[7] = (short)f2bf(b.w);
    return r;
}

#define YROW 296   // sY row stride in shorts (592 B, 16B-aligned)

// ---- M phase: msgs for tile n0's src-CSR segment, y from LDS; erec prefetch ----
// Round 21: store at src-CSR position e -> wave writes 1KB contiguous.
__device__ __forceinline__ void m_phase(const unsigned short* sY,
                                        const int* __restrict__ sstart,
                                        const float4* __restrict__ erec,
                                        uint4* __restrict__ msgOut,
                                        int n0, int t, int N, int E)
{
    const int e0 = sstart[n0];
    const int e1 = (n0 + 32 < N) ? sstart[n0 + 32] : E;
    const int l  = t & 3;

    int e = e0 + (t >> 2);
    if (e >= e1) return;
    float4 r = erec[e];
    while (true) {
        const int en = e + 64;
        float4 rn;
        if (en < e1) rn = erec[en];     // prefetch hides global latency

        const int srcl = __float_as_int(r.x) - n0;
        const float p0 = r.z, p1 = r.w;

        const float qb[3] = {0.5f * (1.f - p0) * (1.f - p0), -p0 * p0 + p0 + 0.5f, 0.5f * p0 * p0};
        const float qa[3] = {0.5f * (1.f - p1) * (1.f - p1), -p1 * p1 + p1 + 0.5f, 0.5f * p1 * p1};

        const uint4* yb = (const uint4*)(sY + srcl * YROW) + l;
        float s[8] = {0.f, 0.f, 0.f, 0.f, 0.f, 0.f, 0.f, 0.f};
        #pragma unroll
        for (int a = 0; a < 3; ++a) {
            float z[8] = {0.f, 0.f, 0.f, 0.f, 0.f, 0.f, 0.f, 0.f};
            #pragma unroll
            for (int b = 0; b < 3; ++b) {
                uint4 v = yb[(a * 3 + b) * 4];
                const float cw = qb[b];
                z[0] = fmaf(cw, blo(v.x), z[0]); z[1] = fmaf(cw, bhi(v.x), z[1]);
                z[2] = fmaf(cw, blo(v.y), z[2]); z[3] = fmaf(cw, bhi(v.y), z[3]);
                z[4] = fmaf(cw, blo(v.z), z[4]); z[5] = fmaf(cw, bhi(v.z), z[5]);
                z[6] = fmaf(cw, blo(v.w), z[6]); z[7] = fmaf(cw, bhi(v.w), z[7]);
            }
            #pragma unroll
            for (int j = 0; j < 8; ++j) s[j] = fmaf(qa[a], z[j], s[j]);
        }

        union { uint4 u; __hip_bfloat162 h[4]; } o;
        #pragma unroll
        for (int j = 0; j < 4; ++j)
            o.h[j] = __float22bfloat162_rn(float2{s[2 * j], s[2 * j + 1]});
        msgOut[(size_t)e * 4 + l] = o.u;   // streaming: addr linear in t, full lines

        if (en >= e1) break;
        r = rn; e = en;
    }
}

// ---- T core (TN=32): per-tile acc, written immediately (~8 live VGPRs) ----
template<int NHALF>  // 2: K=64, 1: K=32
__device__ __forceinline__ void t_core(short8 a0, short8 a1,
                                       const unsigned short* __restrict__ Wt,
                                       const float* __restrict__ bias,
                                       unsigned short* sY, float* __restrict__ aggOut,
                                       int n0, int rh, int cgp, int lc, int q, int N)
{
    const int CIN = NHALF * 32;
    #pragma unroll
    for (int j = 0; j < 10; ++j) {
        const int ti = cgp * 10 + j;
        const unsigned short* wp = Wt + ((size_t)(ti * 16 + lc)) * CIN + q * 8;
        f32x4 acc = (f32x4){0.f, 0.f, 0.f, 0.f};
        acc = __builtin_amdgcn_mfma_f32_16x16x32_bf16(a0, *(const short8*)wp, acc, 0, 0, 0);
        if (NHALF == 2)
            acc = __builtin_amdgcn_mfma_f32_16x16x32_bf16(a1, *(const short8*)(wp + 32), acc, 0, 0, 0);

        if (ti < 18) {
            #pragma unroll
            for (int r = 0; r < 4; ++r) {
                int nl = rh * 16 + q * 4 + r;
                sY[nl * YROW + ti * 16 + lc] = f2bf(acc[r]);
            }
        } else {
            int c = (ti - 18) * 16 + lc;
            float bv = bias[c];
            #pragma unroll
            for (int r = 0; r < 4; ++r) {
                int n = n0 + rh * 16 + q * 4 + r;
                if (n < N) aggOut[(size_t)n * 32 + c] = acc[r] + bv;
            }
        }
    }
}

// L1: X = x [N,64] from global
__global__ __launch_bounds__(256, 8)
void layer_tm0(const float* __restrict__ Xa,
               const unsigned short* __restrict__ Wt, const float* __restrict__ bias,
               const int* __restrict__ sstart, const float4* __restrict__ erec,
               float* __restrict__ aggOut, uint4* __restrict__ msgOut, int N, int E)
{
    __shared__ __align__(16) unsigned short sY[32 * YROW];   // 18,944 B
    const int t = threadIdx.x, wv = t >> 6, lane = t & 63;
    const int lc = lane & 15, q = lane >> 4;
    const int rh = wv & 1, cgp = wv >> 1;
    const int n0 = blockIdx.x * 32;

    int na = n0 + rh * 16 + lc;
    if (na >= N) na = N - 1;
    const float* p = Xa + (size_t)na * 64 + q * 8;
    short8 a0 = cvt8(p);
    short8 a1 = cvt8(p + 32);

    t_core<2>(a0, a1, Wt, bias, sY, aggOut, n0, rh, cgp, lc, q, N);
    __syncthreads();
    m_phase(sY, sstart, erec, msgOut, n0, t, N, E);
}

// L2 (MODE 1): X = [relu(aggPrev + gather msgIn) | skip]; L3 (MODE 2): X = relu(...)
// Round 21: gather reads msg via pos[] indirection (random 64B reads,
// pos prefetched one iteration ahead -> no pos->msg serial chain).
template<int MODE>
__global__ __launch_bounds__(256, 8)
void layer_gtm(const float* __restrict__ aggPrev, const float* __restrict__ skipv,
               const unsigned short* __restrict__ Wt, const float* __restrict__ bias,
               const int* __restrict__ sstart, const int* __restrict__ dstart,
               const float4* __restrict__ erec, const int* __restrict__ pos,
               const uint4* __restrict__ msgIn, uint4* __restrict__ msgOut,
               float* __restrict__ aggOut, int N, int E)
{
    __shared__ __align__(16) unsigned short sY[32 * YROW];
    float* sH = (float*)sY;    // [32][33] fp32 = 4224 B; consumed before sY written
    const int t = threadIdx.x, wv = t >> 6, lane = t & 63;
    const int lc = lane & 15, q = lane >> 4;
    const int rh = wv & 1, cgp = wv >> 1;
    const int n0 = blockIdx.x * 32;

    // ---- cooperative G phase: 256 threads, 8 lanes/node, edge-parity split ----
    {
        const int nl = t >> 3;          // node within tile (0..31)
        const int l  = t & 3;           // channel group (8 ch)
        const int h  = (t >> 2) & 1;    // edge-parity half
        int n = n0 + nl;
        if (n >= N) n = N - 1;          // duplicate-gather padding rows
        float4 A, B;
        if (h == 0) {
            const float* ap = aggPrev + (size_t)n * 32 + l * 8;
            A = *(const float4*)ap;
            B = *(const float4*)(ap + 4);
        } else {
            A = {0.f, 0.f, 0.f, 0.f};
            B = {0.f, 0.f, 0.f, 0.f};
        }
        float4 C = {0.f, 0.f, 0.f, 0.f}, D = {0.f, 0.f, 0.f, 0.f};
        const int e0 = dstart[n] - E;
        const int e1 = ((n + 1 < N) ? dstart[n + 1] : 2 * E) - E;
        const uint4* mp = msgIn + l;
        int g = e0 + h;
        int pc0 = (g < e1)     ? pos[g]     : 0;
        int pc1 = (g + 2 < e1) ? pos[g + 2] : 0;
        for (; g + 2 < e1; g += 4) {    // edges g, g+2 (this half)
            int pn0 = (g + 4 < e1) ? pos[g + 4] : 0;
            int pn1 = (g + 6 < e1) ? pos[g + 6] : 0;
            uint4 v0 = mp[(size_t)pc0 * 4];
            uint4 v1 = mp[(size_t)pc1 * 4];
            A.x += blo(v0.x); A.y += bhi(v0.x); A.z += blo(v0.y); A.w += bhi(v0.y);
            B.x += blo(v0.z); B.y += bhi(v0.z); B.z += blo(v0.w); B.w += bhi(v0.w);
            C.x += blo(v1.x); C.y += bhi(v1.x); C.z += blo(v1.y); C.w += bhi(v1.y);
            D.x += blo(v1.z); D.y += bhi(v1.z); D.z += blo(v1.w); D.w += bhi(v1.w);
            pc0 = pn0; pc1 = pn1;
        }
        if (g < e1) {
            uint4 v = mp[(size_t)pc0 * 4];
            A.x += blo(v.x); A.y += bhi(v.x); A.z += blo(v.y); A.w += bhi(v.y);
            B.x += blo(v.z); B.y += bhi(v.z); B.z += blo(v.w); B.w += bhi(v.w);
        }
        A.x += C.x; A.y += C.y; A.z += C.z; A.w += C.w;
        B.x += D.x; B.y += D.y; B.z += D.z; B.w += D.w;
        // combine halves: lanes t and t^4 hold the two edge parities
        A.x += __shfl_xor(A.x, 4); A.y += __shfl_xor(A.y, 4);
        A.z += __shfl_xor(A.z, 4); A.w += __shfl_xor(A.w, 4);
        B.x += __shfl_xor(B.x, 4); B.y += __shfl_xor(B.y, 4);
        B.z += __shfl_xor(B.z, 4); B.w += __shfl_xor(B.w, 4);
        if (h == 0) {
            float* hp = sH + nl * 33 + l * 8;
            hp[0] = fmaxf(A.x, 0.f); hp[1] = fmaxf(A.y, 0.f);
            hp[2] = fmaxf(A.z, 0.f); hp[3] = fmaxf(A.w, 0.f);
            hp[4] = fmaxf(B.x, 0.f); hp[5] = fmaxf(B.y, 0.f);
            hp[6] = fmaxf(B.z, 0.f); hp[7] = fmaxf(B.w, 0.f);
        }
    }
    __syncthreads();

    // every lane reads its 8 A-frag channels from sH (2-way conflicts max)
    const float* hp = sH + (rh * 16 + lc) * 33 + q * 8;
    union { short8 v; __hip_bfloat162 h2[4]; } pk;
    #pragma unroll
    for (int j = 0; j < 4; ++j)
        pk.h2[j] = __float22bfloat162_rn(float2{hp[2 * j], hp[2 * j + 1]});
    short8 a0 = pk.v;
    short8 a1;
    if (MODE == 1) {
        int na = n0 + rh * 16 + lc;
        if (na >= N) na = N - 1;
        a1 = cvt8(skipv + (size_t)na * 32 + q * 8);
    }
    __syncthreads();   // all sH reads done before t_core overwrites sY

    t_core<(MODE == 1) ? 2 : 1>(a0, a1, Wt, bias, sY, aggOut, n0, rh, cgp, lc, q, N);
    __syncthreads();
    m_phase(sY, sstart, erec, msgOut, n0, t, N, E);
}

// final gather: out = relu(out + sum msg rows), msg via pos[] indirection
__global__ __launch_bounds__(256)
void gather_kernel(const int* __restrict__ dstart, const int* __restrict__ pos,
                   const uint4* __restrict__ msg4, float* __restrict__ agg, int N, int E)
{
    const int t = threadIdx.x;
    const int n = blockIdx.x * 32 + (t >> 3);
    if (n >= N) return;
    const int l = t & 3;            // channel group
    const int h = (t >> 2) & 1;     // edge-parity half

    const int e0 = dstart[n] - E;
    const int e1 = ((n + 1 < N) ? dstart[n + 1] : 2 * E) - E;

    float4* ap = (float4*)(agg + (size_t)n * 32 + l * 8);
    float4 A, B;
    if (h == 0) { A = ap[0]; B = ap[1]; }
    else { A = {0.f, 0.f, 0.f, 0.f}; B = {0.f, 0.f, 0.f, 0.f}; }
    float4 C = {0.f, 0.f, 0.f, 0.f}, D = {0.f, 0.f, 0.f, 0.f};
    const uint4* mp = msg4 + l;
    int g = e0 + h;
    int pc0 = (g < e1)     ? pos[g]     : 0;
    int pc1 = (g + 2 < e1) ? pos[g + 2] : 0;
    for (; g + 2 < e1; g += 4) {
        int pn0 = (g + 4 < e1) ? pos[g + 4] : 0;
        int pn1 = (g + 6 < e1) ? pos[g + 6] : 0;
        uint4 v0 = mp[(size_t)pc0 * 4];
        uint4 v1 = mp[(size_t)pc1 * 4];
        A.x += blo(v0.x); A.y += bhi(v0.x); A.z += blo(v0.y); A.w += bhi(v0.y);
        B.x += blo(v0.z); B.y += bhi(v0.z); B.z += blo(v0.w); B.w += bhi(v0.w);
        C.x += blo(v1.x); C.y += bhi(v1.x); C.z += blo(v1.y); C.w += bhi(v1.y);
        D.x += blo(v1.z); D.y += bhi(v1.z); D.z += blo(v1.w); D.w += bhi(v1.w);
        pc0 = pn0; pc1 = pn1;
    }
    if (g < e1) {
        uint4 v = mp[(size_t)pc0 * 4];
        A.x += blo(v.x); A.y += bhi(v.x); A.z += blo(v.y); A.w += bhi(v.y);
        B.x += blo(v.z); B.y += bhi(v.z); B.z += blo(v.w); B.w += bhi(v.w);
    }
    A.x += C.x; A.y += C.y; A.z += C.z; A.w += C.w;
    B.x += D.x; B.y += D.y; B.z += D.z; B.w += D.w;
    A.x += __shfl_xor(A.x, 4); A.y += __shfl_xor(A.y, 4);
    A.z += __shfl_xor(A.z, 4); A.w += __shfl_xor(A.w, 4);
    B.x += __shfl_xor(B.x, 4); B.y += __shfl_xor(B.y, 4);
    B.z += __shfl_xor(B.z, 4); B.w += __shfl_xor(B.w, 4);
    if (h == 0) {
        A.x = fmaxf(A.x, 0.f); A.y = fmaxf(A.y, 0.f); A.z = fmaxf(A.z, 0.f); A.w = fmaxf(A.w, 0.f);
        B.x = fmaxf(B.x, 0.f); B.y = fmaxf(B.y, 0.f); B.z = fmaxf(B.z, 0.f); B.w = fmaxf(B.w, 0.f);
        ap[0] = A; ap[1] = B;
    }
}

// ---------- prep ----------

__global__ __launch_bounds__(256)
void init_kernel(int* __restrict__ hist, int n2,
                 const float* __restrict__ W1, const float* __restrict__ root1,
                 const float* __restrict__ W2, const float* __restrict__ root2,
                 unsigned short* __restrict__ Wt1, unsigned short* __restrict__ Wt2)
{
    int i = blockIdx.x * 256 + threadIdx.x;
    if (i < n2) { hist[i] = 0; return; }
    int j = i - n2;
    if (j < 320 * 64) {
        int col = j / 64, k = j % 64;
        float v = (col < 288) ? W1[((size_t)(col >> 5) * 64 + k) * 32 + (col & 31)]
                              : root1[(size_t)k * 32 + (col - 288)];
        Wt1[j] = f2bf(v);
    } else if (j < 320 * 96) {
        int jj = j - 320 * 64;
        int col = jj / 32, k = jj % 32;
        float v = (col < 288) ? W2[((size_t)(col >> 5) * 32 + k) * 32 + (col & 31)]
                              : root2[(size_t)k * 32 + (col - 288)];
        Wt2[jj] = f2bf(v);
    }
}

__global__ __launch_bounds__(256)
void count_rank_kernel(const int* __restrict__ ei, int* __restrict__ hist,
                       uint2* __restrict__ rank, int N, int E)
{
    int e = blockIdx.x * 256 + threadIdx.x;
    if (e >= E) return;
    unsigned rs = atomicAdd((unsigned*)&hist[ei[e]], 1u);
    unsigned rd = atomicAdd((unsigned*)&hist[N + ei[E + e]], 1u);
    rank[e] = uint2{rs, rd};
}

__global__ __launch_bounds__(1024)
void scan1_kernel(int* __restrict__ hist, int* __restrict__ bsum, int n)
{
    __shared__ int s[1024];
    int tid = threadIdx.x;
    int i = blockIdx.x * 1024 + tid;
    int v = (i < n) ? hist[i] : 0;
    s[tid] = v;
    __syncthreads();
    for (int off = 1; off < 1024; off <<= 1) {
        int add = (tid >= off) ? s[tid - off] : 0;
        __syncthreads();
        s[tid] += add;
        __syncthreads();
    }
    if (i < n) hist[i] = s[tid] - v;
    if (tid == 1023) bsum[blockIdx.x] = s[1023];
}

__global__ __launch_bounds__(1024)
void scan3_kernel(int* __restrict__ hist, const int* __restrict__ bsum, int n)
{
    __shared__ int sred[128];
    int tid = threadIdx.x;
    int b = blockIdx.x;
    if (tid < 128) sred[tid] = (tid < b) ? bsum[tid] : 0;
    __syncthreads();
    for (int off = 64; off > 0; off >>= 1) {
        if (tid < off) sred[tid] += sred[tid + off];
        __syncthreads();
    }
    int pre = sred[0];
    int i = b * 1024 + tid;
    if (i < n) hist[i] += pre;
}

__global__ __launch_bounds__(256)
void scatter_plain_kernel(const int* __restrict__ ei, const float* __restrict__ pseudo,
                          const int* __restrict__ start, const uint2* __restrict__ rank,
                          float4* __restrict__ erec, int* __restrict__ pos, int N, int E)
{
    int e = blockIdx.x * 256 + threadIdx.x;
    if (e >= E) return;
    int sv = ei[e];
    int dv = ei[E + e];
    uint2 rk = rank[e];
    int ps = start[sv] + (int)rk.x;
    int pd = start[N + dv] + (int)rk.y - E;
    float4 r;
    r.x = __int_as_float(sv);
    r.y = 0.f;                       // dst slot no longer needed by m_phase
    r.z = pseudo[2 * (size_t)e];
    r.w = pseudo[2 * (size_t)e + 1];
    erec[ps] = r;
    pos[pd] = ps;                    // dst-CSR slot -> src-CSR msg position
}

extern "C" void kernel_launch(void* const* d_in, const int* in_sizes, int n_in,
                              void* d_out, int out_size, void* d_ws, size_t ws_size,
                              hipStream_t stream) {
    const float* x      = (const float*)d_in[0];
    const int*   ei     = (const int*)  d_in[1];
    const float* pseudo = (const float*)d_in[2];
    const float* skip   = (const float*)d_in[3];
    const float* W1     = (const float*)d_in[4];
    const float* root1  = (const float*)d_in[5];
    const float* b1     = (const float*)d_in[6];
    const float* W2     = (const float*)d_in[7];
    const float* root2  = (const float*)d_in[8];
    const float* b2     = (const float*)d_in[9];

    const int N = in_sizes[0] / 64;
    const int E = in_sizes[1] / 2;
    float* out = (float*)d_out;

    // ws (~73 MB): msgA[E*32 bf16] msgB[E*32 bf16] agg1[N*32] agg2[N*32]
    //              erec[E f4] start[2N] bsum[256] Wt1 Wt2 pos[E]; rank aliases msgB
    unsigned short* msgA = (unsigned short*)d_ws;
    unsigned short* msgB = msgA + (size_t)E * 32;
    float*  agg1  = (float*)(msgB + (size_t)E * 32);
    float*  agg2  = agg1 + (size_t)N * 32;
    float4* erec  = (float4*)(agg2 + (size_t)N * 32);
    int*    start = (int*)(erec + E);
    int*    bsum  = start + 2 * N;
    unsigned short* Wt1 = (unsigned short*)(bsum + 256);
    unsigned short* Wt2 = Wt1 + 320 * 64;
    int*    pos   = (int*)(Wt2 + 320 * 32);
    uint2*  rank  = (uint2*)msgB;    // prep-only, dead before msgB first written

    const dim3 blk(256);
    const int tb   = (N + 31) / 32;
    const int gb   = (N + 31) / 32;
    const int e256 = (E + 255) / 256;
    const int n2k  = (2 * N + 1023) / 1024;   // <=128 (scan3 prefix cap)
    const int itot = 2 * N + 320 * 96;
    int* dstart = start + N;

    // ---- prep (5 launches) ----
    init_kernel<<<(itot + 255) / 256, blk, 0, stream>>>(start, 2 * N, W1, root1, W2, root2, Wt1, Wt2);
    count_rank_kernel<<<e256, blk, 0, stream>>>(ei, start, rank, N, E);
    scan1_kernel<<<n2k, 1024, 0, stream>>>(start, bsum, 2 * N);
    scan3_kernel<<<n2k, 1024, 0, stream>>>(start, bsum, 2 * N);
    scatter_plain_kernel<<<e256, blk, 0, stream>>>(ei, pseudo, start, rank, erec, pos, N, E);

    // ---- layers (4 launches) ----
    layer_tm0<<<tb, blk, 0, stream>>>(x, Wt1, b1, start, erec, agg1, (uint4*)msgA, N, E);
    layer_gtm<1><<<tb, blk, 0, stream>>>(agg1, skip, Wt1, b1, start, dstart, erec, pos,
                                         (const uint4*)msgA, (uint4*)msgB, agg2, N, E);
    layer_gtm<2><<<tb, blk, 0, stream>>>(agg2, nullptr, Wt2, b2, start, dstart, erec, pos,
                                         (const uint4*)msgB, (uint4*)msgA, out, N, E);
    gather_kernel<<<gb, blk, 0, stream>>>(dstart, pos, (const uint4*)msgA, out, N, E);
}

// Round 4
// 228.655 us; speedup vs baseline: 1.0614x; 1.0614x over previous
//
#include <hip/hip_runtime.h>
#include <hip/hip_bf16.h>

// 3-layer SplineConv (3x3, degree 2, open spline). Atomic-free, deep fusion.
// Round 22: REVERT round-21 (read-side randomness: 242us, -16 regression;
//   scattered 64B msg WRITES merge fine in per-XCD L2 -- working set 3MB/XCD).
//   ONE new variable: launch_bounds (256,8)->(256,6) on the 3 layer kernels.
//   Theory: VGPR_Count=32 (round-1 counters) vs ~40+ live floats in m_phase
//   inner loop (s[8]+z[8]+qa+qb+r+rn+v+o+addrs) => scratch spills in the hot
//   loop. Spills explain: layers ~45us vs ~14us traffic roofline, ~40MB
//   phantom FETCH, VALU 8%/MFMA 1%/conflicts 0 (latency-in-chain signature).
//   LDS 18.9KB caps at 8 blocks/CU anyway; (256,6) raises VGPR cap to ~85
//   (fits live set), 6 blocks/CU = 24 waves/CU TLP remains.
// Pipeline: init | count+rank | scan1 | scan3 | scatter(atomic-free) |
//   L1 tm0 | L2 gtm | L3 gtm | final gather.  TN=32 tiles, 18.9 KB LDS,
//   per-tile MFMA acc write-through, erec prefetch.

typedef __attribute__((ext_vector_type(8))) short short8;
typedef __attribute__((ext_vector_type(4))) float f32x4;

__device__ __forceinline__ float blo(unsigned u) {
    union { unsigned u; float f; } x; x.u = u << 16; return x.f;
}
__device__ __forceinline__ float bhi(unsigned u) {
    union { unsigned u; float f; } x; x.u = u & 0xffff0000u; return x.f;
}
__device__ __forceinline__ unsigned short f2bf(float f) {
    union { float f; unsigned u; } x; x.f = f;
    unsigned r = x.u + 0x7fffu + ((x.u >> 16) & 1u);   // RNE
    return (unsigned short)(r >> 16);
}
__device__ __forceinline__ short8 cvt8(const float* p) {
    float4 a = *(const float4*)p;
    float4 b = *(const float4*)(p + 4);
    short8 r;
    r[0] = (short)f2bf(a.x); r[1] = (short)f2bf(a.y);
    r[2] = (short)f2bf(a.z); r[3] = (short)f2bf(a.w);
    r[4] = (short)f2bf(b.x); r[5] = (short)f2bf(b.y);
    r[6] = (short)f2bf(b.z); r[7] = (short)f2bf(b.w);
    return r;
}

#define YROW 296   // sY row stride in shorts (592 B, 16B-aligned)

// ---- M phase: msgs for tile n0's src-CSR segment, y from LDS; erec prefetch ----
__device__ __forceinline__ void m_phase(const unsigned short* sY,
                                        const int* __restrict__ sstart,
                                        const float4* __restrict__ erec,
                                        uint4* __restrict__ msgOut,
                                        int n0, int t, int N, int E)
{
    const int e0 = sstart[n0];
    const int e1 = (n0 + 32 < N) ? sstart[n0 + 32] : E;
    const int l  = t & 3;

    int e = e0 + (t >> 2);
    if (e >= e1) return;
    float4 r = erec[e];
    while (true) {
        const int en = e + 64;
        float4 rn;
        if (en < e1) rn = erec[en];     // prefetch hides global latency

        const int srcl = __float_as_int(r.x) - n0;
        const int dp   = __float_as_int(r.y);
        const float p0 = r.z, p1 = r.w;

        const float qb[3] = {0.5f * (1.f - p0) * (1.f - p0), -p0 * p0 + p0 + 0.5f, 0.5f * p0 * p0};
        const float qa[3] = {0.5f * (1.f - p1) * (1.f - p1), -p1 * p1 + p1 + 0.5f, 0.5f * p1 * p1};

        const uint4* yb = (const uint4*)(sY + srcl * YROW) + l;
        float s[8] = {0.f, 0.f, 0.f, 0.f, 0.f, 0.f, 0.f, 0.f};
        #pragma unroll
        for (int a = 0; a < 3; ++a) {
            float z[8] = {0.f, 0.f, 0.f, 0.f, 0.f, 0.f, 0.f, 0.f};
            #pragma unroll
            for (int b = 0; b < 3; ++b) {
                uint4 v = yb[(a * 3 + b) * 4];
                const float cw = qb[b];
                z[0] = fmaf(cw, blo(v.x), z[0]); z[1] = fmaf(cw, bhi(v.x), z[1]);
                z[2] = fmaf(cw, blo(v.y), z[2]); z[3] = fmaf(cw, bhi(v.y), z[3]);
                z[4] = fmaf(cw, blo(v.z), z[4]); z[5] = fmaf(cw, bhi(v.z), z[5]);
                z[6] = fmaf(cw, blo(v.w), z[6]); z[7] = fmaf(cw, bhi(v.w), z[7]);
            }
            #pragma unroll
            for (int j = 0; j < 8; ++j) s[j] = fmaf(qa[a], z[j], s[j]);
        }

        union { uint4 u; __hip_bfloat162 h[4]; } o;
        #pragma unroll
        for (int j = 0; j < 4; ++j)
            o.h[j] = __float22bfloat162_rn(float2{s[2 * j], s[2 * j + 1]});
        msgOut[(size_t)dp * 4 + l] = o.u;   // plain store: L2 merges line halves

        if (en >= e1) break;
        r = rn; e = en;
    }
}

// ---- T core (TN=32): per-tile acc, written immediately (~8 live VGPRs) ----
template<int NHALF>  // 2: K=64, 1: K=32
__device__ __forceinline__ void t_core(short8 a0, short8 a1,
                                       const unsigned short* __restrict__ Wt,
                                       const float* __restrict__ bias,
                                       unsigned short* sY, float* __restrict__ aggOut,
                                       int n0, int rh, int cgp, int lc, int q, int N)
{
    const int CIN = NHALF * 32;
    #pragma unroll
    for (int j = 0; j < 10; ++j) {
        const int ti = cgp * 10 + j;
        const unsigned short* wp = Wt + ((size_t)(ti * 16 + lc)) * CIN + q * 8;
        f32x4 acc = (f32x4){0.f, 0.f, 0.f, 0.f};
        acc = __builtin_amdgcn_mfma_f32_16x16x32_bf16(a0, *(const short8*)wp, acc, 0, 0, 0);
        if (NHALF == 2)
            acc = __builtin_amdgcn_mfma_f32_16x16x32_bf16(a1, *(const short8*)(wp + 32), acc, 0, 0, 0);

        if (ti < 18) {
            #pragma unroll
            for (int r = 0; r < 4; ++r) {
                int nl = rh * 16 + q * 4 + r;
                sY[nl * YROW + ti * 16 + lc] = f2bf(acc[r]);
            }
        } else {
            int c = (ti - 18) * 16 + lc;
            float bv = bias[c];
            #pragma unroll
            for (int r = 0; r < 4; ++r) {
                int n = n0 + rh * 16 + q * 4 + r;
                if (n < N) aggOut[(size_t)n * 32 + c] = acc[r] + bv;
            }
        }
    }
}

// L1: X = x [N,64] from global
__global__ __launch_bounds__(256, 6)
void layer_tm0(const float* __restrict__ Xa,
               const unsigned short* __restrict__ Wt, const float* __restrict__ bias,
               const int* __restrict__ sstart, const float4* __restrict__ erec,
               float* __restrict__ aggOut, uint4* __restrict__ msgOut, int N, int E)
{
    __shared__ __align__(16) unsigned short sY[32 * YROW];   // 18,944 B
    const int t = threadIdx.x, wv = t >> 6, lane = t & 63;
    const int lc = lane & 15, q = lane >> 4;
    const int rh = wv & 1, cgp = wv >> 1;
    const int n0 = blockIdx.x * 32;

    int na = n0 + rh * 16 + lc;
    if (na >= N) na = N - 1;
    const float* p = Xa + (size_t)na * 64 + q * 8;
    short8 a0 = cvt8(p);
    short8 a1 = cvt8(p + 32);

    t_core<2>(a0, a1, Wt, bias, sY, aggOut, n0, rh, cgp, lc, q, N);
    __syncthreads();
    m_phase(sY, sstart, erec, msgOut, n0, t, N, E);
}

// L2 (MODE 1): X = [relu(aggPrev + gather msgIn) | skip]; L3 (MODE 2): X = relu(...)
// 8 lanes/node (even/odd edge split), shfl_xor(4) combine into sH.
template<int MODE>
__global__ __launch_bounds__(256, 6)
void layer_gtm(const float* __restrict__ aggPrev, const float* __restrict__ skipv,
               const unsigned short* __restrict__ Wt, const float* __restrict__ bias,
               const int* __restrict__ sstart, const int* __restrict__ dstart,
               const float4* __restrict__ erec,
               const uint4* __restrict__ msgIn, uint4* __restrict__ msgOut,
               float* __restrict__ aggOut, int N, int E)
{
    __shared__ __align__(16) unsigned short sY[32 * YROW];
    float* sH = (float*)sY;    // [32][33] fp32 = 4224 B; consumed before sY written
    const int t = threadIdx.x, wv = t >> 6, lane = t & 63;
    const int lc = lane & 15, q = lane >> 4;
    const int rh = wv & 1, cgp = wv >> 1;
    const int n0 = blockIdx.x * 32;

    // ---- cooperative G phase: 256 threads, 8 lanes/node, edge-parity split ----
    {
        const int nl = t >> 3;          // node within tile (0..31)
        const int l  = t & 3;           // channel group (8 ch)
        const int h  = (t >> 2) & 1;    // edge-parity half
        int n = n0 + nl;
        if (n >= N) n = N - 1;          // duplicate-gather padding rows
        float4 A, B;
        if (h == 0) {
            const float* ap = aggPrev + (size_t)n * 32 + l * 8;
            A = *(const float4*)ap;
            B = *(const float4*)(ap + 4);
        } else {
            A = {0.f, 0.f, 0.f, 0.f};
            B = {0.f, 0.f, 0.f, 0.f};
        }
        float4 C = {0.f, 0.f, 0.f, 0.f}, D = {0.f, 0.f, 0.f, 0.f};
        const int e0 = dstart[n] - E;
        const int e1 = ((n + 1 < N) ? dstart[n + 1] : 2 * E) - E;
        const uint4* mp = msgIn + l;
        int e = e0 + h;
        for (; e + 2 < e1; e += 4) {    // edges e, e+2 (this half), prefetch-deep
            uint4 v0 = mp[(size_t)e * 4];
            uint4 v1 = mp[(size_t)(e + 2) * 4];
            A.x += blo(v0.x); A.y += bhi(v0.x); A.z += blo(v0.y); A.w += bhi(v0.y);
            B.x += blo(v0.z); B.y += bhi(v0.z); B.z += blo(v0.w); B.w += bhi(v0.w);
            C.x += blo(v1.x); C.y += bhi(v1.x); C.z += blo(v1.y); C.w += bhi(v1.y);
            D.x += blo(v1.z); D.y += bhi(v1.z); D.z += blo(v1.w); D.w += bhi(v1.w);
        }
        if (e < e1) {
            uint4 v = mp[(size_t)e * 4];
            A.x += blo(v.x); A.y += bhi(v.x); A.z += blo(v.y); A.w += bhi(v.y);
            B.x += blo(v.z); B.y += bhi(v.z); B.z += blo(v.w); B.w += bhi(v.w);
        }
        A.x += C.x; A.y += C.y; A.z += C.z; A.w += C.w;
        B.x += D.x; B.y += D.y; B.z += D.z; B.w += D.w;
        // combine halves: lanes t and t^4 hold the two edge parities
        A.x += __shfl_xor(A.x, 4); A.y += __shfl_xor(A.y, 4);
        A.z += __shfl_xor(A.z, 4); A.w += __shfl_xor(A.w, 4);
        B.x += __shfl_xor(B.x, 4); B.y += __shfl_xor(B.y, 4);
        B.z += __shfl_xor(B.z, 4); B.w += __shfl_xor(B.w, 4);
        if (h == 0) {
            float* hp = sH + nl * 33 + l * 8;
            hp[0] = fmaxf(A.x, 0.f); hp[1] = fmaxf(A.y, 0.f);
            hp[2] = fmaxf(A.z, 0.f); hp[3] = fmaxf(A.w, 0.f);
            hp[4] = fmaxf(B.x, 0.f); hp[5] = fmaxf(B.y, 0.f);
            hp[6] = fmaxf(B.z, 0.f); hp[7] = fmaxf(B.w, 0.f);
        }
    }
    __syncthreads();

    // every lane reads its 8 A-frag channels from sH (2-way conflicts max)
    const float* hp = sH + (rh * 16 + lc) * 33 + q * 8;
    union { short8 v; __hip_bfloat162 h2[4]; } pk;
    #pragma unroll
    for (int j = 0; j < 4; ++j)
        pk.h2[j] = __float22bfloat162_rn(float2{hp[2 * j], hp[2 * j + 1]});
    short8 a0 = pk.v;
    short8 a1;
    if (MODE == 1) {
        int na = n0 + rh * 16 + lc;
        if (na >= N) na = N - 1;
        a1 = cvt8(skipv + (size_t)na * 32 + q * 8);
    }
    __syncthreads();   // all sH reads done before t_core overwrites sY

    t_core<(MODE == 1) ? 2 : 1>(a0, a1, Wt, bias, sY, aggOut, n0, rh, cgp, lc, q, N);
    __syncthreads();
    m_phase(sY, sstart, erec, msgOut, n0, t, N, E);
}

// final gather: out = relu(out + sum msg rows)
// 32 nodes/block, 8 lanes/node, edge-parity split + shfl combine
__global__ __launch_bounds__(256)
void gather_kernel(const int* __restrict__ dstart, const uint4* __restrict__ msg4,
                   float* __restrict__ agg, int N, int E)
{
    const int t = threadIdx.x;
    const int n = blockIdx.x * 32 + (t >> 3);
    if (n >= N) return;
    const int l = t & 3;            // channel group
    const int h = (t >> 2) & 1;     // edge-parity half

    const int e0 = dstart[n] - E;
    const int e1 = ((n + 1 < N) ? dstart[n + 1] : 2 * E) - E;

    float4* ap = (float4*)(agg + (size_t)n * 32 + l * 8);
    float4 A, B;
    if (h == 0) { A = ap[0]; B = ap[1]; }
    else { A = {0.f, 0.f, 0.f, 0.f}; B = {0.f, 0.f, 0.f, 0.f}; }
    float4 C = {0.f, 0.f, 0.f, 0.f}, D = {0.f, 0.f, 0.f, 0.f};
    const uint4* mp = msg4 + l;
    int e = e0 + h;
    for (; e + 2 < e1; e += 4) {
        uint4 v0 = mp[(size_t)e * 4];
        uint4 v1 = mp[(size_t)(e + 2) * 4];
        A.x += blo(v0.x); A.y += bhi(v0.x); A.z += blo(v0.y); A.w += bhi(v0.y);
        B.x += blo(v0.z); B.y += bhi(v0.z); B.z += blo(v0.w); B.w += bhi(v0.w);
        C.x += blo(v1.x); C.y += bhi(v1.x); C.z += blo(v1.y); C.w += bhi(v1.y);
        D.x += blo(v1.z); D.y += bhi(v1.z); D.z += blo(v1.w); D.w += bhi(v1.w);
    }
    if (e < e1) {
        uint4 v = mp[(size_t)e * 4];
        A.x += blo(v.x); A.y += bhi(v.x); A.z += blo(v.y); A.w += bhi(v.y);
        B.x += blo(v.z); B.y += bhi(v.z); B.z += blo(v.w); B.w += bhi(v.w);
    }
    A.x += C.x; A.y += C.y; A.z += C.z; A.w += C.w;
    B.x += D.x; B.y += D.y; B.z += D.z; B.w += D.w;
    A.x += __shfl_xor(A.x, 4); A.y += __shfl_xor(A.y, 4);
    A.z += __shfl_xor(A.z, 4); A.w += __shfl_xor(A.w, 4);
    B.x += __shfl_xor(B.x, 4); B.y += __shfl_xor(B.y, 4);
    B.z += __shfl_xor(B.z, 4); B.w += __shfl_xor(B.w, 4);
    if (h == 0) {
        A.x = fmaxf(A.x, 0.f); A.y = fmaxf(A.y, 0.f); A.z = fmaxf(A.z, 0.f); A.w = fmaxf(A.w, 0.f);
        B.x = fmaxf(B.x, 0.f); B.y = fmaxf(B.y, 0.f); B.z = fmaxf(B.z, 0.f); B.w = fmaxf(B.w, 0.f);
        ap[0] = A; ap[1] = B;
    }
}

// ---------- prep ----------

__global__ __launch_bounds__(256)
void init_kernel(int* __restrict__ hist, int n2,
                 const float* __restrict__ W1, const float* __restrict__ root1,
                 const float* __restrict__ W2, const float* __restrict__ root2,
                 unsigned short* __restrict__ Wt1, unsigned short* __restrict__ Wt2)
{
    int i = blockIdx.x * 256 + threadIdx.x;
    if (i < n2) { hist[i] = 0; return; }
    int j = i - n2;
    if (j < 320 * 64) {
        int col = j / 64, k = j % 64;
        float v = (col < 288) ? W1[((size_t)(col >> 5) * 64 + k) * 32 + (col & 31)]
                              : root1[(size_t)k * 32 + (col - 288)];
        Wt1[j] = f2bf(v);
    } else if (j < 320 * 96) {
        int jj = j - 320 * 64;
        int col = jj / 32, k = jj % 32;
        float v = (col < 288) ? W2[((size_t)(col >> 5) * 32 + k) * 32 + (col & 31)]
                              : root2[(size_t)k * 32 + (col - 288)];
        Wt2[jj] = f2bf(v);
    }
}

__global__ __launch_bounds__(256)
void count_rank_kernel(const int* __restrict__ ei, int* __restrict__ hist,
                       uint2* __restrict__ rank, int N, int E)
{
    int e = blockIdx.x * 256 + threadIdx.x;
    if (e >= E) return;
    unsigned rs = atomicAdd((unsigned*)&hist[ei[e]], 1u);
    unsigned rd = atomicAdd((unsigned*)&hist[N + ei[E + e]], 1u);
    rank[e] = uint2{rs, rd};
}

__global__ __launch_bounds__(1024)
void scan1_kernel(int* __restrict__ hist, int* __restrict__ bsum, int n)
{
    __shared__ int s[1024];
    int tid = threadIdx.x;
    int i = blockIdx.x * 1024 + tid;
    int v = (i < n) ? hist[i] : 0;
    s[tid] = v;
    __syncthreads();
    for (int off = 1; off < 1024; off <<= 1) {
        int add = (tid >= off) ? s[tid - off] : 0;
        __syncthreads();
        s[tid] += add;
        __syncthreads();
    }
    if (i < n) hist[i] = s[tid] - v;
    if (tid == 1023) bsum[blockIdx.x] = s[1023];
}

__global__ __launch_bounds__(1024)
void scan3_kernel(int* __restrict__ hist, const int* __restrict__ bsum, int n)
{
    __shared__ int sred[128];
    int tid = threadIdx.x;
    int b = blockIdx.x;
    if (tid < 128) sred[tid] = (tid < b) ? bsum[tid] : 0;
    __syncthreads();
    for (int off = 64; off > 0; off >>= 1) {
        if (tid < off) sred[tid] += sred[tid + off];
        __syncthreads();
    }
    int pre = sred[0];
    int i = b * 1024 + tid;
    if (i < n) hist[i] += pre;
}

__global__ __launch_bounds__(256)
void scatter_plain_kernel(const int* __restrict__ ei, const float* __restrict__ pseudo,
                          const int* __restrict__ start, const uint2* __restrict__ rank,
                          float4* __restrict__ erec, int N, int E)
{
    int e = blockIdx.x * 256 + threadIdx.x;
    if (e >= E) return;
    int sv = ei[e];
    int dv = ei[E + e];
    uint2 rk = rank[e];
    int ps = start[sv] + (int)rk.x;
    int pd = start[N + dv] + (int)rk.y - E;
    float4 r;
    r.x = __int_as_float(sv);
    r.y = __int_as_float(pd);
    r.z = pseudo[2 * (size_t)e];
    r.w = pseudo[2 * (size_t)e + 1];
    erec[ps] = r;
}

extern "C" void kernel_launch(void* const* d_in, const int* in_sizes, int n_in,
                              void* d_out, int out_size, void* d_ws, size_t ws_size,
                              hipStream_t stream) {
    const float* x      = (const float*)d_in[0];
    const int*   ei     = (const int*)  d_in[1];
    const float* pseudo = (const float*)d_in[2];
    const float* skip   = (const float*)d_in[3];
    const float* W1     = (const float*)d_in[4];
    const float* root1  = (const float*)d_in[5];
    const float* b1     = (const float*)d_in[6];
    const float* W2     = (const float*)d_in[7];
    const float* root2  = (const float*)d_in[8];
    const float* b2     = (const float*)d_in[9];

    const int N = in_sizes[0] / 64;
    const int E = in_sizes[1] / 2;
    float* out = (float*)d_out;

    // ws (~71 MB): msgA[E*32 bf16] msgB[E*32 bf16] agg1[N*32] agg2[N*32]
    //              erec[E f4] start[2N] bsum[256] Wt1 Wt2; rank aliases msgB
    unsigned short* msgA = (unsigned short*)d_ws;
    unsigned short* msgB = msgA + (size_t)E * 32;
    float*  agg1  = (float*)(msgB + (size_t)E * 32);
    float*  agg2  = agg1 + (size_t)N * 32;
    float4* erec  = (float4*)(agg2 + (size_t)N * 32);
    int*    start = (int*)(erec + E);
    int*    bsum  = start + 2 * N;
    unsigned short* Wt1 = (unsigned short*)(bsum + 256);
    unsigned short* Wt2 = Wt1 + 320 * 64;
    uint2*  rank  = (uint2*)msgB;    // prep-only, dead before msgB first written

    const dim3 blk(256);
    const int tb   = (N + 31) / 32;
    const int gb   = (N + 31) / 32;
    const int e256 = (E + 255) / 256;
    const int n2k  = (2 * N + 1023) / 1024;   // <=128 (scan3 prefix cap)
    const int itot = 2 * N + 320 * 96;
    int* dstart = start + N;

    // ---- prep (5 launches) ----
    init_kernel<<<(itot + 255) / 256, blk, 0, stream>>>(start, 2 * N, W1, root1, W2, root2, Wt1, Wt2);
    count_rank_kernel<<<e256, blk, 0, stream>>>(ei, start, rank, N, E);
    scan1_kernel<<<n2k, 1024, 0, stream>>>(start, bsum, 2 * N);
    scan3_kernel<<<n2k, 1024, 0, stream>>>(start, bsum, 2 * N);
    scatter_plain_kernel<<<e256, blk, 0, stream>>>(ei, pseudo, start, rank, erec, N, E);

    // ---- layers (4 launches) ----
    layer_tm0<<<tb, blk, 0, stream>>>(x, Wt1, b1, start, erec, agg1, (uint4*)msgA, N, E);
    layer_gtm<1><<<tb, blk, 0, stream>>>(agg1, skip, Wt1, b1, start, dstart, erec,
                                         (const uint4*)msgA, (uint4*)msgB, agg2, N, E);
    layer_gtm<2><<<tb, blk, 0, stream>>>(agg2, nullptr, Wt2, b2, start, dstart, erec,
                                         (const uint4*)msgB, (uint4*)msgA, out, N, E);
    gather_kernel<<<gb, blk, 0, stream>>>(dstart, (const uint4*)msgA, out, N, E);
}

// Round 5
// 225.971 us; speedup vs baseline: 1.0740x; 1.0119x over previous
//
#include <hip/hip_runtime.h>
#include <hip/hip_bf16.h>

// 3-layer SplineConv (3x3, degree 2, open spline). Atomic-free, deep fusion.
// Round 23: memory-level parallelism. Layers run ~40us vs ~10us fair-share
//   roofline with VALU 8% / MFMA 1% / 0 conflicts and store semantics proven
//   irrelevant (r19/r21) => latency*concurrency bound. m_phase had 1 erec
//   load in flight (1-deep prefetch), G phase 2 msg loads. Now: m_phase
//   processes 2 edge streams/iter with 2-deep prefetch (2 loads + 2 stores
//   in flight); G phase + gather unroll-4 (4 independent 64B msg loads in
//   flight per thread). Everything else identical to the 228.6us config.
// Pipeline: init | count+rank | scan1 | scan3 | scatter(atomic-free) |
//   L1 tm0 | L2 gtm | L3 gtm | final gather.  TN=32 tiles, 18.9 KB LDS.

typedef __attribute__((ext_vector_type(8))) short short8;
typedef __attribute__((ext_vector_type(4))) float f32x4;

__device__ __forceinline__ float blo(unsigned u) {
    union { unsigned u; float f; } x; x.u = u << 16; return x.f;
}
__device__ __forceinline__ float bhi(unsigned u) {
    union { unsigned u; float f; } x; x.u = u & 0xffff0000u; return x.f;
}
__device__ __forceinline__ unsigned short f2bf(float f) {
    union { float f; unsigned u; } x; x.f = f;
    unsigned r = x.u + 0x7fffu + ((x.u >> 16) & 1u);   // RNE
    return (unsigned short)(r >> 16);
}
__device__ __forceinline__ short8 cvt8(const float* p) {
    float4 a = *(const float4*)p;
    float4 b = *(const float4*)(p + 4);
    short8 r;
    r[0] = (short)f2bf(a.x); r[1] = (short)f2bf(a.y);
    r[2] = (short)f2bf(a.z); r[3] = (short)f2bf(a.w);
    r[4] = (short)f2bf(b.x); r[5] = (short)f2bf(b.y);
    r[6] = (short)f2bf(b.z); r[7] = (short)f2bf(b.w);
    return r;
}

#define YROW 296   // sY row stride in shorts (592 B, 16B-aligned)

// ---- one edge's message: 9 LDS b128 reads, 72 FMA, one 16B store ----
__device__ __forceinline__ void m_edge(const unsigned short* sY, const float4 r,
                                       uint4* __restrict__ msgOut, int n0, int l)
{
    const int srcl = __float_as_int(r.x) - n0;
    const int dp   = __float_as_int(r.y);
    const float p0 = r.z, p1 = r.w;

    const float qb[3] = {0.5f * (1.f - p0) * (1.f - p0), -p0 * p0 + p0 + 0.5f, 0.5f * p0 * p0};
    const float qa[3] = {0.5f * (1.f - p1) * (1.f - p1), -p1 * p1 + p1 + 0.5f, 0.5f * p1 * p1};

    const uint4* yb = (const uint4*)(sY + srcl * YROW) + l;
    float s[8] = {0.f, 0.f, 0.f, 0.f, 0.f, 0.f, 0.f, 0.f};
    #pragma unroll
    for (int a = 0; a < 3; ++a) {
        float z[8] = {0.f, 0.f, 0.f, 0.f, 0.f, 0.f, 0.f, 0.f};
        #pragma unroll
        for (int b = 0; b < 3; ++b) {
            uint4 v = yb[(a * 3 + b) * 4];
            const float cw = qb[b];
            z[0] = fmaf(cw, blo(v.x), z[0]); z[1] = fmaf(cw, bhi(v.x), z[1]);
            z[2] = fmaf(cw, blo(v.y), z[2]); z[3] = fmaf(cw, bhi(v.y), z[3]);
            z[4] = fmaf(cw, blo(v.z), z[4]); z[5] = fmaf(cw, bhi(v.z), z[5]);
            z[6] = fmaf(cw, blo(v.w), z[6]); z[7] = fmaf(cw, bhi(v.w), z[7]);
        }
        #pragma unroll
        for (int j = 0; j < 8; ++j) s[j] = fmaf(qa[a], z[j], s[j]);
    }

    union { uint4 u; __hip_bfloat162 h[4]; } o;
    #pragma unroll
    for (int j = 0; j < 4; ++j)
        o.h[j] = __float22bfloat162_rn(float2{s[2 * j], s[2 * j + 1]});
    msgOut[(size_t)dp * 4 + l] = o.u;
}

// ---- M phase: 2 edge streams per iteration, 2-deep erec prefetch ----
__device__ __forceinline__ void m_phase(const unsigned short* sY,
                                        const int* __restrict__ sstart,
                                        const float4* __restrict__ erec,
                                        uint4* __restrict__ msgOut,
                                        int n0, int t, int N, int E)
{
    const int e0 = sstart[n0];
    const int e1 = (n0 + 32 < N) ? sstart[n0 + 32] : E;
    const int l  = t & 3;

    int e = e0 + (t >> 2);     // stride 64 slots across the block
    if (e >= e1) return;
    float4 r0 = erec[e];
    bool  has1 = (e + 64 < e1);
    float4 r1;
    if (has1) r1 = erec[e + 64];

    while (true) {
        const int ep0 = e + 128, ep1 = e + 192;
        const bool hp0 = ep0 < e1, hp1 = ep1 < e1;
        float4 rp0, rp1;
        if (hp0) rp0 = erec[ep0];          // 2-deep prefetch: both in flight
        if (hp1) rp1 = erec[ep1];

        m_edge(sY, r0, msgOut, n0, l);
        if (!has1) break;
        m_edge(sY, r1, msgOut, n0, l);

        if (!hp0) break;
        r0 = rp0; r1 = rp1; has1 = hp1; e = ep0;
    }
}

// ---- T core (TN=32): per-tile acc, written immediately (~8 live VGPRs) ----
template<int NHALF>  // 2: K=64, 1: K=32
__device__ __forceinline__ void t_core(short8 a0, short8 a1,
                                       const unsigned short* __restrict__ Wt,
                                       const float* __restrict__ bias,
                                       unsigned short* sY, float* __restrict__ aggOut,
                                       int n0, int rh, int cgp, int lc, int q, int N)
{
    const int CIN = NHALF * 32;
    #pragma unroll
    for (int j = 0; j < 10; ++j) {
        const int ti = cgp * 10 + j;
        const unsigned short* wp = Wt + ((size_t)(ti * 16 + lc)) * CIN + q * 8;
        f32x4 acc = (f32x4){0.f, 0.f, 0.f, 0.f};
        acc = __builtin_amdgcn_mfma_f32_16x16x32_bf16(a0, *(const short8*)wp, acc, 0, 0, 0);
        if (NHALF == 2)
            acc = __builtin_amdgcn_mfma_f32_16x16x32_bf16(a1, *(const short8*)(wp + 32), acc, 0, 0, 0);

        if (ti < 18) {
            #pragma unroll
            for (int r = 0; r < 4; ++r) {
                int nl = rh * 16 + q * 4 + r;
                sY[nl * YROW + ti * 16 + lc] = f2bf(acc[r]);
            }
        } else {
            int c = (ti - 18) * 16 + lc;
            float bv = bias[c];
            #pragma unroll
            for (int r = 0; r < 4; ++r) {
                int n = n0 + rh * 16 + q * 4 + r;
                if (n < N) aggOut[(size_t)n * 32 + c] = acc[r] + bv;
            }
        }
    }
}

// L1: X = x [N,64] from global
__global__ __launch_bounds__(256, 6)
void layer_tm0(const float* __restrict__ Xa,
               const unsigned short* __restrict__ Wt, const float* __restrict__ bias,
               const int* __restrict__ sstart, const float4* __restrict__ erec,
               float* __restrict__ aggOut, uint4* __restrict__ msgOut, int N, int E)
{
    __shared__ __align__(16) unsigned short sY[32 * YROW];   // 18,944 B
    const int t = threadIdx.x, wv = t >> 6, lane = t & 63;
    const int lc = lane & 15, q = lane >> 4;
    const int rh = wv & 1, cgp = wv >> 1;
    const int n0 = blockIdx.x * 32;

    int na = n0 + rh * 16 + lc;
    if (na >= N) na = N - 1;
    const float* p = Xa + (size_t)na * 64 + q * 8;
    short8 a0 = cvt8(p);
    short8 a1 = cvt8(p + 32);

    t_core<2>(a0, a1, Wt, bias, sY, aggOut, n0, rh, cgp, lc, q, N);
    __syncthreads();
    m_phase(sY, sstart, erec, msgOut, n0, t, N, E);
}

// L2 (MODE 1): X = [relu(aggPrev + gather msgIn) | skip]; L3 (MODE 2): X = relu(...)
// G phase: 8 lanes/node, edge-parity split, unroll-4 (4 msg loads in flight).
template<int MODE>
__global__ __launch_bounds__(256, 6)
void layer_gtm(const float* __restrict__ aggPrev, const float* __restrict__ skipv,
               const unsigned short* __restrict__ Wt, const float* __restrict__ bias,
               const int* __restrict__ sstart, const int* __restrict__ dstart,
               const float4* __restrict__ erec,
               const uint4* __restrict__ msgIn, uint4* __restrict__ msgOut,
               float* __restrict__ aggOut, int N, int E)
{
    __shared__ __align__(16) unsigned short sY[32 * YROW];
    float* sH = (float*)sY;    // [32][33] fp32 = 4224 B; consumed before sY written
    const int t = threadIdx.x, wv = t >> 6, lane = t & 63;
    const int lc = lane & 15, q = lane >> 4;
    const int rh = wv & 1, cgp = wv >> 1;
    const int n0 = blockIdx.x * 32;

    // ---- cooperative G phase: 256 threads, 8 lanes/node, edge-parity split ----
    {
        const int nl = t >> 3;          // node within tile (0..31)
        const int l  = t & 3;           // channel group (8 ch)
        const int h  = (t >> 2) & 1;    // edge-parity half
        int n = n0 + nl;
        if (n >= N) n = N - 1;          // duplicate-gather padding rows
        float4 A, B;
        if (h == 0) {
            const float* ap = aggPrev + (size_t)n * 32 + l * 8;
            A = *(const float4*)ap;
            B = *(const float4*)(ap + 4);
        } else {
            A = {0.f, 0.f, 0.f, 0.f};
            B = {0.f, 0.f, 0.f, 0.f};
        }
        float4 C = {0.f, 0.f, 0.f, 0.f}, D = {0.f, 0.f, 0.f, 0.f};
        const int e0 = dstart[n] - E;
        const int e1 = ((n + 1 < N) ? dstart[n + 1] : 2 * E) - E;
        const uint4* mp = msgIn + l;
        int e = e0 + h;
        // unroll-4: edges e, e+2, e+4, e+6 -- 4 independent loads in flight
        for (; e + 6 < e1; e += 8) {
            uint4 v0 = mp[(size_t)e * 4];
            uint4 v1 = mp[(size_t)(e + 2) * 4];
            uint4 v2 = mp[(size_t)(e + 4) * 4];
            uint4 v3 = mp[(size_t)(e + 6) * 4];
            A.x += blo(v0.x); A.y += bhi(v0.x); A.z += blo(v0.y); A.w += bhi(v0.y);
            B.x += blo(v0.z); B.y += bhi(v0.z); B.z += blo(v0.w); B.w += bhi(v0.w);
            C.x += blo(v1.x); C.y += bhi(v1.x); C.z += blo(v1.y); C.w += bhi(v1.y);
            D.x += blo(v1.z); D.y += bhi(v1.z); D.z += blo(v1.w); D.w += bhi(v1.w);
            A.x += blo(v2.x); A.y += bhi(v2.x); A.z += blo(v2.y); A.w += bhi(v2.y);
            B.x += blo(v2.z); B.y += bhi(v2.z); B.z += blo(v2.w); B.w += bhi(v2.w);
            C.x += blo(v3.x); C.y += bhi(v3.x); C.z += blo(v3.y); C.w += bhi(v3.y);
            D.x += blo(v3.z); D.y += bhi(v3.z); D.z += blo(v3.w); D.w += bhi(v3.w);
        }
        for (; e < e1; e += 2) {
            uint4 v = mp[(size_t)e * 4];
            A.x += blo(v.x); A.y += bhi(v.x); A.z += blo(v.y); A.w += bhi(v.y);
            B.x += blo(v.z); B.y += bhi(v.z); B.z += blo(v.w); B.w += bhi(v.w);
        }
        A.x += C.x; A.y += C.y; A.z += C.z; A.w += C.w;
        B.x += D.x; B.y += D.y; B.z += D.z; B.w += D.w;
        // combine halves: lanes t and t^4 hold the two edge parities
        A.x += __shfl_xor(A.x, 4); A.y += __shfl_xor(A.y, 4);
        A.z += __shfl_xor(A.z, 4); A.w += __shfl_xor(A.w, 4);
        B.x += __shfl_xor(B.x, 4); B.y += __shfl_xor(B.y, 4);
        B.z += __shfl_xor(B.z, 4); B.w += __shfl_xor(B.w, 4);
        if (h == 0) {
            float* hp = sH + nl * 33 + l * 8;
            hp[0] = fmaxf(A.x, 0.f); hp[1] = fmaxf(A.y, 0.f);
            hp[2] = fmaxf(A.z, 0.f); hp[3] = fmaxf(A.w, 0.f);
            hp[4] = fmaxf(B.x, 0.f); hp[5] = fmaxf(B.y, 0.f);
            hp[6] = fmaxf(B.z, 0.f); hp[7] = fmaxf(B.w, 0.f);
        }
    }
    __syncthreads();

    // every lane reads its 8 A-frag channels from sH (2-way conflicts max)
    const float* hp = sH + (rh * 16 + lc) * 33 + q * 8;
    union { short8 v; __hip_bfloat162 h2[4]; } pk;
    #pragma unroll
    for (int j = 0; j < 4; ++j)
        pk.h2[j] = __float22bfloat162_rn(float2{hp[2 * j], hp[2 * j + 1]});
    short8 a0 = pk.v;
    short8 a1;
    if (MODE == 1) {
        int na = n0 + rh * 16 + lc;
        if (na >= N) na = N - 1;
        a1 = cvt8(skipv + (size_t)na * 32 + q * 8);
    }
    __syncthreads();   // all sH reads done before t_core overwrites sY

    t_core<(MODE == 1) ? 2 : 1>(a0, a1, Wt, bias, sY, aggOut, n0, rh, cgp, lc, q, N);
    __syncthreads();
    m_phase(sY, sstart, erec, msgOut, n0, t, N, E);
}

// final gather: out = relu(out + sum msg rows)
// 32 nodes/block, 8 lanes/node, edge-parity split, unroll-4
__global__ __launch_bounds__(256)
void gather_kernel(const int* __restrict__ dstart, const uint4* __restrict__ msg4,
                   float* __restrict__ agg, int N, int E)
{
    const int t = threadIdx.x;
    const int n = blockIdx.x * 32 + (t >> 3);
    if (n >= N) return;
    const int l = t & 3;            // channel group
    const int h = (t >> 2) & 1;     // edge-parity half

    const int e0 = dstart[n] - E;
    const int e1 = ((n + 1 < N) ? dstart[n + 1] : 2 * E) - E;

    float4* ap = (float4*)(agg + (size_t)n * 32 + l * 8);
    float4 A, B;
    if (h == 0) { A = ap[0]; B = ap[1]; }
    else { A = {0.f, 0.f, 0.f, 0.f}; B = {0.f, 0.f, 0.f, 0.f}; }
    float4 C = {0.f, 0.f, 0.f, 0.f}, D = {0.f, 0.f, 0.f, 0.f};
    const uint4* mp = msg4 + l;
    int e = e0 + h;
    for (; e + 6 < e1; e += 8) {
        uint4 v0 = mp[(size_t)e * 4];
        uint4 v1 = mp[(size_t)(e + 2) * 4];
        uint4 v2 = mp[(size_t)(e + 4) * 4];
        uint4 v3 = mp[(size_t)(e + 6) * 4];
        A.x += blo(v0.x); A.y += bhi(v0.x); A.z += blo(v0.y); A.w += bhi(v0.y);
        B.x += blo(v0.z); B.y += bhi(v0.z); B.z += blo(v0.w); B.w += bhi(v0.w);
        C.x += blo(v1.x); C.y += bhi(v1.x); C.z += blo(v1.y); C.w += bhi(v1.y);
        D.x += blo(v1.z); D.y += bhi(v1.z); D.z += blo(v1.w); D.w += bhi(v1.w);
        A.x += blo(v2.x); A.y += bhi(v2.x); A.z += blo(v2.y); A.w += bhi(v2.y);
        B.x += blo(v2.z); B.y += bhi(v2.z); B.z += blo(v2.w); B.w += bhi(v2.w);
        C.x += blo(v3.x); C.y += bhi(v3.x); C.z += blo(v3.y); C.w += bhi(v3.y);
        D.x += blo(v3.z); D.y += bhi(v3.z); D.z += blo(v3.w); D.w += bhi(v3.w);
    }
    for (; e < e1; e += 2) {
        uint4 v = mp[(size_t)e * 4];
        A.x += blo(v.x); A.y += bhi(v.x); A.z += blo(v.y); A.w += bhi(v.y);
        B.x += blo(v.z); B.y += bhi(v.z); B.z += blo(v.w); B.w += bhi(v.w);
    }
    A.x += C.x; A.y += C.y; A.z += C.z; A.w += C.w;
    B.x += D.x; B.y += D.y; B.z += D.z; B.w += D.w;
    A.x += __shfl_xor(A.x, 4); A.y += __shfl_xor(A.y, 4);
    A.z += __shfl_xor(A.z, 4); A.w += __shfl_xor(A.w, 4);
    B.x += __shfl_xor(B.x, 4); B.y += __shfl_xor(B.y, 4);
    B.z += __shfl_xor(B.z, 4); B.w += __shfl_xor(B.w, 4);
    if (h == 0) {
        A.x = fmaxf(A.x, 0.f); A.y = fmaxf(A.y, 0.f); A.z = fmaxf(A.z, 0.f); A.w = fmaxf(A.w, 0.f);
        B.x = fmaxf(B.x, 0.f); B.y = fmaxf(B.y, 0.f); B.z = fmaxf(B.z, 0.f); B.w = fmaxf(B.w, 0.f);
        ap[0] = A; ap[1] = B;
    }
}

// ---------- prep ----------

__global__ __launch_bounds__(256)
void init_kernel(int* __restrict__ hist, int n2,
                 const float* __restrict__ W1, const float* __restrict__ root1,
                 const float* __restrict__ W2, const float* __restrict__ root2,
                 unsigned short* __restrict__ Wt1, unsigned short* __restrict__ Wt2)
{
    int i = blockIdx.x * 256 + threadIdx.x;
    if (i < n2) { hist[i] = 0; return; }
    int j = i - n2;
    if (j < 320 * 64) {
        int col = j / 64, k = j % 64;
        float v = (col < 288) ? W1[((size_t)(col >> 5) * 64 + k) * 32 + (col & 31)]
                              : root1[(size_t)k * 32 + (col - 288)];
        Wt1[j] = f2bf(v);
    } else if (j < 320 * 96) {
        int jj = j - 320 * 64;
        int col = jj / 32, k = jj % 32;
        float v = (col < 288) ? W2[((size_t)(col >> 5) * 32 + k) * 32 + (col & 31)]
                              : root2[(size_t)k * 32 + (col - 288)];
        Wt2[jj] = f2bf(v);
    }
}

__global__ __launch_bounds__(256)
void count_rank_kernel(const int* __restrict__ ei, int* __restrict__ hist,
                       uint2* __restrict__ rank, int N, int E)
{
    int e = blockIdx.x * 256 + threadIdx.x;
    if (e >= E) return;
    unsigned rs = atomicAdd((unsigned*)&hist[ei[e]], 1u);
    unsigned rd = atomicAdd((unsigned*)&hist[N + ei[E + e]], 1u);
    rank[e] = uint2{rs, rd};
}

__global__ __launch_bounds__(1024)
void scan1_kernel(int* __restrict__ hist, int* __restrict__ bsum, int n)
{
    __shared__ int s[1024];
    int tid = threadIdx.x;
    int i = blockIdx.x * 1024 + tid;
    int v = (i < n) ? hist[i] : 0;
    s[tid] = v;
    __syncthreads();
    for (int off = 1; off < 1024; off <<= 1) {
        int add = (tid >= off) ? s[tid - off] : 0;
        __syncthreads();
        s[tid] += add;
        __syncthreads();
    }
    if (i < n) hist[i] = s[tid] - v;
    if (tid == 1023) bsum[blockIdx.x] = s[1023];
}

__global__ __launch_bounds__(1024)
void scan3_kernel(int* __restrict__ hist, const int* __restrict__ bsum, int n)
{
    __shared__ int sred[128];
    int tid = threadIdx.x;
    int b = blockIdx.x;
    if (tid < 128) sred[tid] = (tid < b) ? bsum[tid] : 0;
    __syncthreads();
    for (int off = 64; off > 0; off >>= 1) {
        if (tid < off) sred[tid] += sred[tid + off];
        __syncthreads();
    }
    int pre = sred[0];
    int i = b * 1024 + tid;
    if (i < n) hist[i] += pre;
}

__global__ __launch_bounds__(256)
void scatter_plain_kernel(const int* __restrict__ ei, const float* __restrict__ pseudo,
                          const int* __restrict__ start, const uint2* __restrict__ rank,
                          float4* __restrict__ erec, int N, int E)
{
    int e = blockIdx.x * 256 + threadIdx.x;
    if (e >= E) return;
    int sv = ei[e];
    int dv = ei[E + e];
    uint2 rk = rank[e];
    int ps = start[sv] + (int)rk.x;
    int pd = start[N + dv] + (int)rk.y - E;
    float4 r;
    r.x = __int_as_float(sv);
    r.y = __int_as_float(pd);
    r.z = pseudo[2 * (size_t)e];
    r.w = pseudo[2 * (size_t)e + 1];
    erec[ps] = r;
}

extern "C" void kernel_launch(void* const* d_in, const int* in_sizes, int n_in,
                              void* d_out, int out_size, void* d_ws, size_t ws_size,
                              hipStream_t stream) {
    const float* x      = (const float*)d_in[0];
    const int*   ei     = (const int*)  d_in[1];
    const float* pseudo = (const float*)d_in[2];
    const float* skip   = (const float*)d_in[3];
    const float* W1     = (const float*)d_in[4];
    const float* root1  = (const float*)d_in[5];
    const float* b1     = (const float*)d_in[6];
    const float* W2     = (const float*)d_in[7];
    const float* root2  = (const float*)d_in[8];
    const float* b2     = (const float*)d_in[9];

    const int N = in_sizes[0] / 64;
    const int E = in_sizes[1] / 2;
    float* out = (float*)d_out;

    // ws (~71 MB): msgA[E*32 bf16] msgB[E*32 bf16] agg1[N*32] agg2[N*32]
    //              erec[E f4] start[2N] bsum[256] Wt1 Wt2; rank aliases msgB
    unsigned short* msgA = (unsigned short*)d_ws;
    unsigned short* msgB = msgA + (size_t)E * 32;
    float*  agg1  = (float*)(msgB + (size_t)E * 32);
    float*  agg2  = agg1 + (size_t)N * 32;
    float4* erec  = (float4*)(agg2 + (size_t)N * 32);
    int*    start = (int*)(erec + E);
    int*    bsum  = start + 2 * N;
    unsigned short* Wt1 = (unsigned short*)(bsum + 256);
    unsigned short* Wt2 = Wt1 + 320 * 64;
    uint2*  rank  = (uint2*)msgB;    // prep-only, dead before msgB first written

    const dim3 blk(256);
    const int tb   = (N + 31) / 32;
    const int gb   = (N + 31) / 32;
    const int e256 = (E + 255) / 256;
    const int n2k  = (2 * N + 1023) / 1024;   // <=128 (scan3 prefix cap)
    const int itot = 2 * N + 320 * 96;
    int* dstart = start + N;

    // ---- prep (5 launches) ----
    init_kernel<<<(itot + 255) / 256, blk, 0, stream>>>(start, 2 * N, W1, root1, W2, root2, Wt1, Wt2);
    count_rank_kernel<<<e256, blk, 0, stream>>>(ei, start, rank, N, E);
    scan1_kernel<<<n2k, 1024, 0, stream>>>(start, bsum, 2 * N);
    scan3_kernel<<<n2k, 1024, 0, stream>>>(start, bsum, 2 * N);
    scatter_plain_kernel<<<e256, blk, 0, stream>>>(ei, pseudo, start, rank, erec, N, E);

    // ---- layers (4 launches) ----
    layer_tm0<<<tb, blk, 0, stream>>>(x, Wt1, b1, start, erec, agg1, (uint4*)msgA, N, E);
    layer_gtm<1><<<tb, blk, 0, stream>>>(agg1, skip, Wt1, b1, start, dstart, erec,
                                         (const uint4*)msgA, (uint4*)msgB, agg2, N, E);
    layer_gtm<2><<<tb, blk, 0, stream>>>(agg2, nullptr, Wt2, b2, start, dstart, erec,
                                         (const uint4*)msgB, (uint4*)msgA, out, N, E);
    gather_kernel<<<gb, blk, 0, stream>>>(dstart, (const uint4*)msgA, out, N, E);
}